// Round 1
// baseline (260.508 us; speedup 1.0000x reference)
//
#include <hip/hip_runtime.h>
#include <math.h>

#define BB 4
#define LL 2048
#define HH 8
#define DD 64
#define SK 40          // sample_k
#define UU 40          // top-k count
#define UB 4           // u-rows per attn block
#define SCALE 0.125f   // 1/sqrt(64)

// Q,K,V input layout: [b][l][h][d]  -> (((b*LL + l)*HH + h)<<6) + d
// out layout:         [b][h][l][d]  -> ((bh*LL + l)<<6) + d, bh = b*HH+h
// ws: M[b][h][l] (65536 f), part[bh][c][d] (16384 f), Vmean[bh][d] (2048 f), Mtop[bh][u] (1280 i)

// ---------------- Kernel 1: sampled scores -> M ----------------
// one wave per (b,h,l) row. lanes = 16 s-groups x 4 d-quarters.
__global__ __launch_bounds__(256) void k_m(
    const float* __restrict__ Q, const float* __restrict__ K,
    const int* __restrict__ idxs, float* __restrict__ Mout)
{
  int wrow = (blockIdx.x << 2) + (threadIdx.x >> 6);   // 0..65535 = ((b*HH+h)*LL+l)
  int lane = threadIdx.x & 63;
  int l = wrow & (LL - 1);
  int h = (wrow >> 11) & (HH - 1);
  int b = wrow >> 14;
  int sg = lane >> 2;    // 0..15
  int dg = lane & 3;     // 0..3

  const float* qrow = Q + (((size_t)(b * LL + l) * HH + h) << 6);
  float4 qv[4];
#pragma unroll
  for (int i = 0; i < 4; ++i)
    qv[i] = *(const float4*)(qrow + i * 16 + dg * 4);

  const int* ip = idxs + l * SK;
  float mx = -INFINITY, sum = 0.f;

#pragma unroll
  for (int c = 0; c < 3; ++c) {
    int s = c * 16 + sg;
    int idx = (s < SK) ? ip[s] : ip[0];
    const float* krow = K + (((size_t)(b * LL + idx) * HH + h) << 6);
    float p = 0.f;
#pragma unroll
    for (int i = 0; i < 4; ++i) {
      float4 kv = *(const float4*)(krow + i * 16 + dg * 4);
      p += qv[i].x * kv.x + qv[i].y * kv.y + qv[i].z * kv.z + qv[i].w * kv.w;
    }
    // reduce across the 4 d-quarters (lanes differing in bits 0,1)
    p += __shfl_xor(p, 1);
    p += __shfl_xor(p, 2);
    if (s < SK) { mx = fmaxf(mx, p); sum += p; }
  }
  // reduce across the 16 s-groups (bits 2..5)
#pragma unroll
  for (int off = 4; off <= 32; off <<= 1) {
    mx = fmaxf(mx, __shfl_xor(mx, off));
    sum += __shfl_xor(sum, off);
  }
  if (lane == 0) Mout[wrow] = mx - sum * (1.0f / (float)LL);
}

// ---------------- Kernel 2: top-40 per (b,h) ----------------
__global__ __launch_bounds__(64) void k_topk(
    const float* __restrict__ Mv, int* __restrict__ Mtop)
{
  __shared__ float sv[LL];
  int bh = blockIdx.x;
  int lane = threadIdx.x;
  for (int i = lane; i < LL; i += 64) sv[i] = Mv[bh * LL + i];
  __syncthreads();
  for (int r = 0; r < UU; ++r) {
    float bv = -INFINITY; int bi = 0;
#pragma unroll
    for (int j = 0; j < 32; ++j) {
      int i = lane + (j << 6);
      float v = sv[i];
      if (v > bv) { bv = v; bi = i; }
    }
#pragma unroll
    for (int off = 1; off < 64; off <<= 1) {
      float ov = __shfl_xor(bv, off);
      int oi = __shfl_xor(bi, off);
      if (ov > bv || (ov == bv && oi < bi)) { bv = ov; bi = oi; }
    }
    if (lane == 0) { Mtop[bh * UU + r] = bi; sv[bi] = -INFINITY; }
    __syncthreads();
  }
}

// ---------------- Kernel 3a: partial V sums ----------------
__global__ __launch_bounds__(256) void k_vpart(
    const float* __restrict__ V, float* __restrict__ part)
{
  int blk = blockIdx.x;            // bh*8 + c
  int bh = blk >> 3, c = blk & 7;
  int b = bh >> 3, h = bh & 7;
  int t = threadIdx.x, d = t & 63, w = t >> 6;
  int l0 = (c << 8) + (w << 6);
  float a0 = 0, a1 = 0, a2 = 0, a3 = 0;
  for (int j = 0; j < 64; j += 4) {
    int l = l0 + j;
    a0 += V[(((size_t)(b * LL + l + 0) * HH + h) << 6) + d];
    a1 += V[(((size_t)(b * LL + l + 1) * HH + h) << 6) + d];
    a2 += V[(((size_t)(b * LL + l + 2) * HH + h) << 6) + d];
    a3 += V[(((size_t)(b * LL + l + 3) * HH + h) << 6) + d];
  }
  __shared__ float sm[4][64];
  sm[w][d] = a0 + a1 + a2 + a3;
  __syncthreads();
  if (t < 64) part[(blk << 6) + t] = sm[0][t] + sm[1][t] + sm[2][t] + sm[3][t];
}

// ---------------- Kernel 3b: combine -> Vmean ----------------
__global__ __launch_bounds__(256) void k_vcomb(
    const float* __restrict__ part, float* __restrict__ Vmean)
{
  int e = blockIdx.x * 256 + threadIdx.x;  // 0..2047
  int bh = e >> 6, d = e & 63;
  float s = 0;
#pragma unroll
  for (int c = 0; c < 8; ++c) s += part[(((bh << 3) + c) << 6) + d];
  Vmean[e] = s * (1.0f / (float)LL);
}

// ---------------- Kernel 4: broadcast fill ----------------
__global__ __launch_bounds__(256) void k_fill(
    const float4* __restrict__ Vmean4, float4* __restrict__ out4)
{
  int i = blockIdx.x * 256 + threadIdx.x;  // 0..1048575 float4s
  int d4 = i & 15;
  int bh = i >> 15;
  out4[i] = Vmean4[(bh << 4) + d4];
}

// ---------------- Kernel 5: dense attention for selected rows ----------------
__global__ __launch_bounds__(256) void k_attn(
    const float* __restrict__ Q, const float* __restrict__ K,
    const float* __restrict__ V, const int* __restrict__ Mtop,
    float* __restrict__ out)
{
  __shared__ float Ks[64][65];     // +1 pad: stride 65 -> conflict-free
  __shared__ float Ss[UB][LL];
  __shared__ float Qs[UB][64];
  __shared__ int   gqi[UB];

  int blk = blockIdx.x;
  int bh = blk / 10, ug = blk % 10;
  int b = bh >> 3, h = bh & 7;
  int t = threadIdx.x;
  int u = t >> 6, ln = t & 63;     // u == wave id

  if (t < UB) gqi[t] = Mtop[bh * UU + ug * UB + t];
  __syncthreads();
  {
    int gq = gqi[u];
    Qs[u][ln] = Q[(((size_t)(b * LL + gq) * HH + h) << 6) + ln];
  }
  __syncthreads();

  // hoist this wave's Q row into registers
  float4 qv[16];
#pragma unroll
  for (int i = 0; i < 16; ++i) qv[i] = *(const float4*)&Qs[u][i * 4];

  // scores: tile K through LDS; wave u computes row u
  for (int lt = 0; lt < 32; ++lt) {
    int l0 = lt << 6;
#pragma unroll
    for (int i = 0; i < 4; ++i) {
      int j = t + (i << 8);                 // 0..1023
      int r = j >> 4, c4 = (j & 15) << 2;
      float4 kv = *(const float4*)&K[(((size_t)(b * LL + l0 + r) * HH + h) << 6) + c4];
      Ks[r][c4 + 0] = kv.x; Ks[r][c4 + 1] = kv.y;
      Ks[r][c4 + 2] = kv.z; Ks[r][c4 + 3] = kv.w;
    }
    __syncthreads();
    float s = 0.f;
#pragma unroll
    for (int i = 0; i < 16; ++i) {
      s += qv[i].x * Ks[ln][i * 4 + 0] + qv[i].y * Ks[ln][i * 4 + 1]
         + qv[i].z * Ks[ln][i * 4 + 2] + qv[i].w * Ks[ln][i * 4 + 3];
    }
    Ss[u][l0 + ln] = s * SCALE;
    __syncthreads();
  }

  // softmax over the wave's own row (no cross-wave deps)
  float svv[32];
  float m = -INFINITY;
#pragma unroll
  for (int j = 0; j < 32; ++j) {
    svv[j] = Ss[u][ln + (j << 6)];
    m = fmaxf(m, svv[j]);
  }
#pragma unroll
  for (int off = 1; off < 64; off <<= 1) m = fmaxf(m, __shfl_xor(m, off));
  float ssum = 0.f;
#pragma unroll
  for (int j = 0; j < 32; ++j) {
    float p = __expf(svv[j] - m);
    Ss[u][ln + (j << 6)] = p;
    ssum += p;
  }
#pragma unroll
  for (int off = 1; off < 64; off <<= 1) ssum += __shfl_xor(ssum, off);
  float inv = 1.0f / ssum;

  // PV: lane = d, stream V rows (coalesced 256B/wave)
  float c0 = 0, c1 = 0, c2 = 0, c3 = 0;
  const float* vbase = V + (((size_t)(b * LL) * HH + h) << 6) + ln;
  for (int l = 0; l < LL; l += 4) {
    float p0 = Ss[u][l + 0], p1 = Ss[u][l + 1];
    float p2 = Ss[u][l + 2], p3 = Ss[u][l + 3];
    c0 += p0 * vbase[(size_t)(l + 0) * (HH * DD)];
    c1 += p1 * vbase[(size_t)(l + 1) * (HH * DD)];
    c2 += p2 * vbase[(size_t)(l + 2) * (HH * DD)];
    c3 += p3 * vbase[(size_t)(l + 3) * (HH * DD)];
  }
  float ctx = (c0 + c1 + c2 + c3) * inv;
  out[(((size_t)bh * LL + gqi[u]) << 6) + ln] = ctx;
}

extern "C" void kernel_launch(void* const* d_in, const int* in_sizes, int n_in,
                              void* d_out, int out_size, void* d_ws, size_t ws_size,
                              hipStream_t stream)
{
  (void)in_sizes; (void)n_in; (void)out_size; (void)ws_size;
  const float* Q = (const float*)d_in[0];
  const float* K = (const float*)d_in[1];
  const float* V = (const float*)d_in[2];
  const int* idxs = (const int*)d_in[3];
  float* out = (float*)d_out;

  float* wsf = (float*)d_ws;
  float* M     = wsf;                 // 65536
  float* part  = wsf + 65536;         // 16384
  float* Vmean = wsf + 81920;         // 2048
  int*   Mtop  = (int*)(wsf + 83968); // 1280

  k_m    <<<16384, 256, 0, stream>>>(Q, K, idxs, M);
  k_topk <<<32,     64, 0, stream>>>(M, Mtop);
  k_vpart<<<256,   256, 0, stream>>>(V, part);
  k_vcomb<<<8,     256, 0, stream>>>(part, Vmean);
  k_fill <<<4096,  256, 0, stream>>>((const float4*)Vmean, (float4*)out);
  k_attn <<<320,   256, 0, stream>>>(Q, K, V, Mtop, out);
}

// Round 2
// 217.531 us; speedup vs baseline: 1.1976x; 1.1976x over previous
//
#include <hip/hip_runtime.h>
#include <math.h>

#define LL 2048
#define HH 8
#define DD 64
#define SK 40
#define UU 40
#define SCALE 0.125f

// layouts: Q/K/V [b][l][h][d]; out [b][h][l][d]
// ws: M 65536 | part 16384 | Vmean 2048 | Mtop 1280i | pm 10240 | pl 10240 | pO 655360

// ---------------- Kernel 1: sampled scores -> M ----------------
// block = (b,l), 8 waves = 8 heads share the gathered K lines (2KB contiguous per idx)
__global__ __launch_bounds__(512) void k_m(
    const float* __restrict__ Q, const float* __restrict__ K,
    const int* __restrict__ idxs, float* __restrict__ Mout)
{
  int bx = blockIdx.x;                 // b*2048 + l
  int b = bx >> 11, l = bx & (LL - 1);
  int t = threadIdx.x;
  int h = t >> 6, lane = t & 63;
  int sg = lane >> 2, dg = lane & 3;

  const float* qrow = Q + (((size_t)(b * LL + l) * HH + h) << 6);
  float4 qv[4];
#pragma unroll
  for (int i = 0; i < 4; ++i)
    qv[i] = *(const float4*)(qrow + i * 16 + dg * 4);

  const int* ip = idxs + l * SK;
  float mx = -INFINITY, sum = 0.f;

#pragma unroll
  for (int c = 0; c < 3; ++c) {
    int s = c * 16 + sg;
    int idx = (s < SK) ? ip[s] : ip[0];
    const float* krow = K + (((size_t)(b * LL + idx) * HH + h) << 6);
    float p = 0.f;
#pragma unroll
    for (int i = 0; i < 4; ++i) {
      float4 kv = *(const float4*)(krow + i * 16 + dg * 4);
      p += qv[i].x * kv.x + qv[i].y * kv.y + qv[i].z * kv.z + qv[i].w * kv.w;
    }
    p += __shfl_xor(p, 1);
    p += __shfl_xor(p, 2);
    if (s < SK) { mx = fmaxf(mx, p); sum += p; }
  }
#pragma unroll
  for (int off = 4; off <= 32; off <<= 1) {
    mx = fmaxf(mx, __shfl_xor(mx, off));
    sum += __shfl_xor(sum, off);
  }
  if (lane == 0) Mout[(((size_t)b * HH + h) << 11) + l] = mx - sum * (1.0f / (float)LL);
}

// ---------------- Kernel 2: top-40 per (b,h), 4 waves ----------------
__global__ __launch_bounds__(256) void k_topk(
    const float* __restrict__ Mv, int* __restrict__ Mtop)
{
  __shared__ float sv[LL];
  __shared__ float wm[4];
  __shared__ int wi[4];
  int bh = blockIdx.x;
  int t = threadIdx.x, w = t >> 6, ln = t & 63;
  for (int i = t; i < LL; i += 256) sv[i] = Mv[bh * LL + i];
  __syncthreads();
  for (int r = 0; r < UU; ++r) {
    float bv = -INFINITY; int bi = 0;
#pragma unroll
    for (int j = 0; j < 8; ++j) {
      int i = t + (j << 8);
      float v = sv[i];
      if (v > bv) { bv = v; bi = i; }
    }
#pragma unroll
    for (int off = 1; off < 64; off <<= 1) {
      float ov = __shfl_xor(bv, off);
      int oi = __shfl_xor(bi, off);
      if (ov > bv || (ov == bv && oi < bi)) { bv = ov; bi = oi; }
    }
    if (ln == 0) { wm[w] = bv; wi[w] = bi; }
    __syncthreads();
    if (t == 0) {
      float Bv = wm[0]; int Bi = wi[0];
#pragma unroll
      for (int k = 1; k < 4; ++k)
        if (wm[k] > Bv || (wm[k] == Bv && wi[k] < Bi)) { Bv = wm[k]; Bi = wi[k]; }
      Mtop[bh * UU + r] = Bi;
      sv[Bi] = -INFINITY;
    }
    __syncthreads();
  }
}

// ---------------- Kernel 3a: partial V sums ----------------
__global__ __launch_bounds__(256) void k_vpart(
    const float* __restrict__ V, float* __restrict__ part)
{
  int blk = blockIdx.x;
  int bh = blk >> 3, c = blk & 7;
  int b = bh >> 3, h = bh & 7;
  int t = threadIdx.x, d = t & 63, w = t >> 6;
  int l0 = (c << 8) + (w << 6);
  float a0 = 0, a1 = 0, a2 = 0, a3 = 0;
  for (int j = 0; j < 64; j += 4) {
    int l = l0 + j;
    a0 += V[(((size_t)(b * LL + l + 0) * HH + h) << 6) + d];
    a1 += V[(((size_t)(b * LL + l + 1) * HH + h) << 6) + d];
    a2 += V[(((size_t)(b * LL + l + 2) * HH + h) << 6) + d];
    a3 += V[(((size_t)(b * LL + l + 3) * HH + h) << 6) + d];
  }
  __shared__ float sm[4][64];
  sm[w][d] = a0 + a1 + a2 + a3;
  __syncthreads();
  if (t < 64) part[(blk << 6) + t] = sm[0][t] + sm[1][t] + sm[2][t] + sm[3][t];
}

// ---------------- Kernel 3b: combine -> Vmean ----------------
__global__ __launch_bounds__(256) void k_vcomb(
    const float* __restrict__ part, float* __restrict__ Vmean)
{
  int e = blockIdx.x * 256 + threadIdx.x;
  int bh = e >> 6, d = e & 63;
  float s = 0;
#pragma unroll
  for (int c = 0; c < 8; ++c) s += part[(((bh << 3) + c) << 6) + d];
  Vmean[e] = s * (1.0f / (float)LL);
}

// ---------------- Kernel 4: broadcast fill ----------------
__global__ __launch_bounds__(256) void k_fill(
    const float4* __restrict__ Vmean4, float4* __restrict__ out4)
{
  int i = blockIdx.x * 256 + threadIdx.x;
  int d4 = i & 15;
  int bh = i >> 15;
  out4[i] = Vmean4[(bh << 4) + d4];
}

// ---------------- Kernel 5: split-K attention partials ----------------
// grid = 32 bh * 5 rowgroups * 8 chunks; block = 512 thr (8 waves)
// wave u computes scores for row u over its 256-col chunk; PV retiles
// to (rowgroup of 4) x (col quarter) per wave with 4-row V-register reuse.
__global__ __launch_bounds__(512) void k_attn2(
    const float* __restrict__ Q, const float* __restrict__ K,
    const float* __restrict__ V, const int* __restrict__ Mtop,
    float* __restrict__ pm, float* __restrict__ pl, float4* __restrict__ pO4)
{
  __shared__ float4 Ks4[1024];        // swizzled: [col*16 + (d4^(col&7))]
  __shared__ float Ps[8][256];
  __shared__ float4 Os4[4][2][4][16]; // [cq][rw][r][d4]
  __shared__ int gqi[8];

  int blk = blockIdx.x;
  int bh = blk / 40;
  int rem = blk % 40;
  int ch = rem / 5, rg = rem % 5;     // 5 consecutive blocks share a K chunk
  int b = bh >> 3, h = bh & 7;
  int t = threadIdx.x;
  int w = t >> 6, ln = t & 63;
  int l0 = ch << 8;

  if (t < 8) gqi[t] = Mtop[bh * UU + rg * 8 + t];
  __syncthreads();

  // this wave's Q row -> regs (wave-uniform addresses)
  float4 qv[16];
  {
    const float4* qrow = (const float4*)(Q + (((size_t)(b * LL + gqi[w]) * HH + h) << 6));
#pragma unroll
    for (int i = 0; i < 16; ++i) qv[i] = qrow[i];
  }

  // ---- scores over 4 sub-tiles of 64 K rows, reg-prefetch staging ----
  const float4* K4 = (const float4*)K;
  size_t kbase = ((size_t)(b * LL + l0) * HH + h) << 4;  // f4 idx, row stride 128
  int col0 = t >> 4, d40 = t & 15;
  float4 g0, g1;
  g0 = K4[kbase + (size_t)(col0) * 128 + d40];
  g1 = K4[kbase + (size_t)(col0 + 32) * 128 + d40];

  float sc[4];
#pragma unroll
  for (int st = 0; st < 4; ++st) {
    __syncthreads();                           // Ks free
    Ks4[col0 * 16 + (d40 ^ (col0 & 7))] = g0;
    Ks4[(col0 + 32) * 16 + (d40 ^ (col0 & 7))] = g1;
    float4 n0, n1;
    if (st < 3) {
      int lr = (st + 1) * 64;
      n0 = K4[kbase + (size_t)(lr + col0) * 128 + d40];
      n1 = K4[kbase + (size_t)(lr + col0 + 32) * 128 + d40];
    }
    __syncthreads();                           // Ks ready
    float s = 0.f;
#pragma unroll
    for (int d4 = 0; d4 < 16; ++d4) {
      float4 kv = Ks4[ln * 16 + (d4 ^ (ln & 7))];
      s += qv[d4].x * kv.x + qv[d4].y * kv.y + qv[d4].z * kv.z + qv[d4].w * kv.w;
    }
    sc[st] = s * SCALE;
    g0 = n0; g1 = n1;
  }

  // ---- partial softmax over this wave's 256 cols ----
  float m = fmaxf(fmaxf(sc[0], sc[1]), fmaxf(sc[2], sc[3]));
#pragma unroll
  for (int off = 1; off < 64; off <<= 1) m = fmaxf(m, __shfl_xor(m, off));
  float lsum = 0.f;
#pragma unroll
  for (int st = 0; st < 4; ++st) {
    float p = __expf(sc[st] - m);
    Ps[w][st * 64 + ln] = p;
    lsum += p;
  }
#pragma unroll
  for (int off = 1; off < 64; off <<= 1) lsum += __shfl_xor(lsum, off);
  if (ln == 0) {
    int prow = bh * UU + rg * 8 + w;
    pm[prow * 8 + ch] = m;
    pl[prow * 8 + ch] = lsum;
  }
  __syncthreads();

  // ---- PV: wave = (rowgroup rw of 4 rows) x (col quarter cq) ----
  int rw = w >> 2, cq = w & 3;
  int cg = ln >> 4, d4 = ln & 15;
  float4 o0 = {0,0,0,0}, o1 = {0,0,0,0}, o2 = {0,0,0,0}, o3 = {0,0,0,0};
  const float4* vbase = K4; // reuse type; compute V base separately
  vbase = (const float4*)V + (((size_t)(b * LL + l0 + cq * 64) * HH + h) << 4) / 16 * 16; // placeholder avoided below
  size_t vb = (((size_t)(b * LL + l0 + cq * 64) * HH + h) << 4);
  const float4* V4 = (const float4*)V;
#pragma unroll
  for (int i = 0; i < 16; ++i) {
    int c = i * 4 + cg;
    float4 v4 = V4[vb + (size_t)c * 128 + d4];
    float p0 = Ps[rw * 4 + 0][cq * 64 + c];
    float p1 = Ps[rw * 4 + 1][cq * 64 + c];
    float p2 = Ps[rw * 4 + 2][cq * 64 + c];
    float p3 = Ps[rw * 4 + 3][cq * 64 + c];
    o0.x += p0 * v4.x; o0.y += p0 * v4.y; o0.z += p0 * v4.z; o0.w += p0 * v4.w;
    o1.x += p1 * v4.x; o1.y += p1 * v4.y; o1.z += p1 * v4.z; o1.w += p1 * v4.w;
    o2.x += p2 * v4.x; o2.y += p2 * v4.y; o2.z += p2 * v4.z; o2.w += p2 * v4.w;
    o3.x += p3 * v4.x; o3.y += p3 * v4.y; o3.z += p3 * v4.z; o3.w += p3 * v4.w;
  }
  // reduce across the 4 col-groups (lanes xor 16, 32)
#pragma unroll
  for (int off = 16; off <= 32; off <<= 1) {
    o0.x += __shfl_xor(o0.x, off); o0.y += __shfl_xor(o0.y, off);
    o0.z += __shfl_xor(o0.z, off); o0.w += __shfl_xor(o0.w, off);
    o1.x += __shfl_xor(o1.x, off); o1.y += __shfl_xor(o1.y, off);
    o1.z += __shfl_xor(o1.z, off); o1.w += __shfl_xor(o1.w, off);
    o2.x += __shfl_xor(o2.x, off); o2.y += __shfl_xor(o2.y, off);
    o2.z += __shfl_xor(o2.z, off); o2.w += __shfl_xor(o2.w, off);
    o3.x += __shfl_xor(o3.x, off); o3.y += __shfl_xor(o3.y, off);
    o3.z += __shfl_xor(o3.z, off); o3.w += __shfl_xor(o3.w, off);
  }
  if (cg == 0) {
    Os4[cq][rw][0][d4] = o0;
    Os4[cq][rw][1][d4] = o1;
    Os4[cq][rw][2][d4] = o2;
    Os4[cq][rw][3][d4] = o3;
  }
  __syncthreads();

  if (t < 128) {
    int r = t >> 4, dd = t & 15;
    float4 a = Os4[0][r >> 2][r & 3][dd];
    float4 bq = Os4[1][r >> 2][r & 3][dd];
    float4 cc = Os4[2][r >> 2][r & 3][dd];
    float4 dq = Os4[3][r >> 2][r & 3][dd];
    float4 s;
    s.x = a.x + bq.x + cc.x + dq.x;
    s.y = a.y + bq.y + cc.y + dq.y;
    s.z = a.z + bq.z + cc.z + dq.z;
    s.w = a.w + bq.w + cc.w + dq.w;
    int prow = bh * UU + rg * 8 + r;
    pO4[(prow * 8 + ch) * 16 + dd] = s;
  }
}

// ---------------- Kernel 6: merge chunk partials ----------------
__global__ __launch_bounds__(256) void k_comb(
    const float* __restrict__ pm, const float* __restrict__ pl,
    const float* __restrict__ pO, const int* __restrict__ Mtop,
    float* __restrict__ out)
{
  int row = blockIdx.x * 4 + (threadIdx.x >> 6);  // 0..1279
  int ln = threadIdx.x & 63;
  int bh = row / UU, r40 = row % UU;
  float mm[8];
#pragma unroll
  for (int c = 0; c < 8; ++c) mm[c] = pm[row * 8 + c];
  float ms = mm[0];
#pragma unroll
  for (int c = 1; c < 8; ++c) ms = fmaxf(ms, mm[c]);
  float wsum = 0.f, o = 0.f;
#pragma unroll
  for (int c = 0; c < 8; ++c) {
    float wc = __expf(mm[c] - ms);
    wsum += wc * pl[row * 8 + c];
    o += wc * pO[(row * 8 + c) * 64 + ln];
  }
  int gq = Mtop[bh * UU + r40];
  out[(((size_t)bh * LL + gq) << 6) + ln] = o / wsum;
}

extern "C" void kernel_launch(void* const* d_in, const int* in_sizes, int n_in,
                              void* d_out, int out_size, void* d_ws, size_t ws_size,
                              hipStream_t stream)
{
  (void)in_sizes; (void)n_in; (void)out_size; (void)ws_size;
  const float* Q = (const float*)d_in[0];
  const float* K = (const float*)d_in[1];
  const float* V = (const float*)d_in[2];
  const int* idxs = (const int*)d_in[3];
  float* out = (float*)d_out;

  float* wsf = (float*)d_ws;
  float* M     = wsf;                   // 65536
  float* part  = wsf + 65536;           // 16384
  float* Vmean = wsf + 81920;           // 2048
  int*   Mtop  = (int*)(wsf + 83968);   // 1280
  float* pm    = wsf + 85248;           // 10240
  float* pl    = wsf + 95488;           // 10240
  float* pO    = wsf + 105728;          // 655360

  k_m    <<<8192, 512, 0, stream>>>(Q, K, idxs, M);
  k_topk <<<32,   256, 0, stream>>>(M, Mtop);
  k_vpart<<<256,  256, 0, stream>>>(V, part);
  k_vcomb<<<8,    256, 0, stream>>>(part, Vmean);
  k_fill <<<4096, 256, 0, stream>>>((const float4*)Vmean, (float4*)out);
  k_attn2<<<1280, 512, 0, stream>>>(Q, K, V, Mtop, pm, pl, (float4*)pO);
  k_comb <<<320,  256, 0, stream>>>(pm, pl, pO, Mtop, out);
}

// Round 3
// 215.683 us; speedup vs baseline: 1.2078x; 1.0086x over previous
//
#include <hip/hip_runtime.h>
#include <math.h>

#define LL 2048
#define HH 8
#define DD 64
#define SK 40
#define UU 40
#define SCALE 0.125f

// layouts: Q/K/V [b][l][h][d]; out [b][h][l][d]
// ws: M 65536 | part 16384 | (unused 2048) | Mtop 1280i | pm 10240 | pl 10240 | pO 655360

// ---------------- Kernel 1: sampled scores -> M ----------------
// XCD-pinned: xcd = bx&7 owns b = xcd>>1 -> per-XCD gather working set = K[b] = 4MB = L2.
// block = (b,l); 8 waves = 8 heads share the gathered K lines (2KB contiguous per idx).
__global__ __launch_bounds__(512) void k_m(
    const float* __restrict__ Q, const float* __restrict__ K,
    const int* __restrict__ idxs, float* __restrict__ Mout)
{
  int bx = blockIdx.x;
  int xcd = bx & 7, slot = bx >> 3;       // slot 0..1023
  int b = xcd >> 1;
  int l = ((xcd & 1) << 10) | slot;
  int t = threadIdx.x;
  int h = t >> 6, lane = t & 63;
  int sg = lane >> 2, dg = lane & 3;

  int kb = b << 20;                        // b * 2048*8*64
  int qoff = kb + (l << 9) + (h << 6) + (dg << 2);
  float4 qv[4];
#pragma unroll
  for (int i = 0; i < 4; ++i)
    qv[i] = *(const float4*)(Q + qoff + i * 16);

  const int* ip = idxs + l * SK;
  int kconst = kb + (h << 6) + (dg << 2);
  float mx = -INFINITY, sum = 0.f;

#pragma unroll
  for (int c = 0; c < 3; ++c) {
    int s = c * 16 + sg;
    float p = 0.f;
    if (s < SK) {
      int koff = kconst + (ip[s] << 9);
      const float* krow = K + koff;
#pragma unroll
      for (int i = 0; i < 4; ++i) {
        float4 kv = *(const float4*)(krow + i * 16);
        p += qv[i].x * kv.x + qv[i].y * kv.y + qv[i].z * kv.z + qv[i].w * kv.w;
      }
    }
    p += __shfl_xor(p, 1);
    p += __shfl_xor(p, 2);
    if (s < SK) { mx = fmaxf(mx, p); sum += p; }
  }
#pragma unroll
  for (int off = 4; off <= 32; off <<= 1) {
    mx = fmaxf(mx, __shfl_xor(mx, off));
    sum += __shfl_xor(sum, off);
  }
  if (lane == 0) Mout[((b * HH + h) << 11) + l] = mx - sum * (1.0f / (float)LL);
}

// ---------------- Kernel 2: top-40 per (b,h), 4 waves ----------------
__global__ __launch_bounds__(256) void k_topk(
    const float* __restrict__ Mv, int* __restrict__ Mtop)
{
  __shared__ float sv[LL];
  __shared__ float wm[4];
  __shared__ int wi[4];
  int bh = blockIdx.x;
  int t = threadIdx.x, w = t >> 6, ln = t & 63;
  for (int i = t; i < LL; i += 256) sv[i] = Mv[bh * LL + i];
  __syncthreads();
  for (int r = 0; r < UU; ++r) {
    float bv = -INFINITY; int bi = 0;
#pragma unroll
    for (int j = 0; j < 8; ++j) {
      int i = t + (j << 8);
      float v = sv[i];
      if (v > bv) { bv = v; bi = i; }
    }
#pragma unroll
    for (int off = 1; off < 64; off <<= 1) {
      float ov = __shfl_xor(bv, off);
      int oi = __shfl_xor(bi, off);
      if (ov > bv || (ov == bv && oi < bi)) { bv = ov; bi = oi; }
    }
    if (ln == 0) { wm[w] = bv; wi[w] = bi; }
    __syncthreads();
    if (t == 0) {
      float Bv = wm[0]; int Bi = wi[0];
#pragma unroll
      for (int k = 1; k < 4; ++k)
        if (wm[k] > Bv || (wm[k] == Bv && wi[k] < Bi)) { Bv = wm[k]; Bi = wi[k]; }
      Mtop[bh * UU + r] = Bi;
      sv[Bi] = -INFINITY;
    }
    __syncthreads();
  }
}

// ---------------- Kernel 3: partial V sums ----------------
__global__ __launch_bounds__(256) void k_vpart(
    const float* __restrict__ V, float* __restrict__ part)
{
  int blk = blockIdx.x;
  int bh = blk >> 3, c = blk & 7;
  int b = bh >> 3, h = bh & 7;
  int t = threadIdx.x, d = t & 63, w = t >> 6;
  int l0 = (c << 8) + (w << 6);
  int base = (b << 20) + (l0 << 9) + (h << 6) + d;
  float a0 = 0, a1 = 0, a2 = 0, a3 = 0;
  for (int j = 0; j < 64; j += 4) {
    a0 += V[base + ((j + 0) << 9)];
    a1 += V[base + ((j + 1) << 9)];
    a2 += V[base + ((j + 2) << 9)];
    a3 += V[base + ((j + 3) << 9)];
  }
  __shared__ float sm[4][64];
  sm[w][d] = a0 + a1 + a2 + a3;
  __syncthreads();
  if (t < 64) part[(blk << 6) + t] = sm[0][t] + sm[1][t] + sm[2][t] + sm[3][t];
}

// ---------------- Kernel 4: Vmean (fused) + broadcast fill ----------------
// each block covers 256 consecutive float4 of out -> single bh per block
__global__ __launch_bounds__(256) void k_fill(
    const float4* __restrict__ part4, float4* __restrict__ out4)
{
  int i = blockIdx.x * 256 + threadIdx.x;   // float4 index, 0..1048575
  int bh = i >> 15;
  __shared__ float4 vm[16];
  if (threadIdx.x < 16) {
    int d4 = threadIdx.x;
    float4 s = {0, 0, 0, 0};
#pragma unroll
    for (int c = 0; c < 8; ++c) {
      float4 p = part4[((bh << 3) + c) * 16 + d4];
      s.x += p.x; s.y += p.y; s.z += p.z; s.w += p.w;
    }
    const float inv = 1.0f / (float)LL;
    s.x *= inv; s.y *= inv; s.z *= inv; s.w *= inv;
    vm[d4] = s;
  }
  __syncthreads();
  out4[i] = vm[i & 15];
}

// ---------------- Kernel 5: split-K attention partials ----------------
// XCD-pinned: ch = bx&7 -> the 5 rowgroup blocks sharing a (bh,ch) K/V chunk
// land on one XCD; per-XCD working set = 32bh * 128KB = 4MB = L2.
__global__ __launch_bounds__(512) void k_attn2(
    const float* __restrict__ Q, const float* __restrict__ K,
    const float* __restrict__ V, const int* __restrict__ Mtop,
    float* __restrict__ pm, float* __restrict__ pl, float4* __restrict__ pO4)
{
  __shared__ float4 Ks4[1024];        // swizzled: [col*16 + (d4^(col&7))]
  __shared__ float Ps[8][256];
  __shared__ float4 Os4[4][2][4][16]; // [cq][rw][r][d4]
  __shared__ int gqi[8];

  int bx = blockIdx.x;
  int ch = bx & 7;
  int slot = bx >> 3;                 // 0..159
  int bh = slot / 5, rg = slot % 5;
  int b = bh >> 3, h = bh & 7;
  int t = threadIdx.x;
  int w = t >> 6, ln = t & 63;
  int l0 = ch << 8;

  if (t < 8) gqi[t] = Mtop[bh * UU + rg * 8 + t];
  __syncthreads();

  // this wave's Q row -> regs (wave-uniform addresses)
  float4 qv[16];
  {
    const float4* qrow = (const float4*)Q + (((b << 11) + gqi[w]) << 7) + (h << 4);
#pragma unroll
    for (int i = 0; i < 16; ++i) qv[i] = qrow[i];
  }

  // ---- scores over 4 sub-tiles of 64 K rows, reg-prefetch staging ----
  const float4* K4 = (const float4*)K;
  int kbase = (((b << 11) + l0) << 7) + (h << 4);   // float4 units, row stride 128
  int col0 = t >> 4, d40 = t & 15;
  int sw0 = col0 * 16 + (d40 ^ (col0 & 7));
  float4 g0 = K4[kbase + col0 * 128 + d40];
  float4 g1 = K4[kbase + (col0 + 32) * 128 + d40];

  float sc[4];
#pragma unroll
  for (int st = 0; st < 4; ++st) {
    __syncthreads();                           // Ks free
    Ks4[sw0] = g0;
    Ks4[sw0 + 512] = g1;
    float4 n0, n1;
    if (st < 3) {
      int lr = (st + 1) * 64;
      n0 = K4[kbase + (lr + col0) * 128 + d40];
      n1 = K4[kbase + (lr + col0 + 32) * 128 + d40];
    }
    __syncthreads();                           // Ks ready
    float s = 0.f;
#pragma unroll
    for (int d4 = 0; d4 < 16; ++d4) {
      float4 kv = Ks4[ln * 16 + (d4 ^ (ln & 7))];
      s += qv[d4].x * kv.x + qv[d4].y * kv.y + qv[d4].z * kv.z + qv[d4].w * kv.w;
    }
    sc[st] = s * SCALE;
    g0 = n0; g1 = n1;
  }

  // ---- partial softmax over this wave's 256 cols ----
  float m = fmaxf(fmaxf(sc[0], sc[1]), fmaxf(sc[2], sc[3]));
#pragma unroll
  for (int off = 1; off < 64; off <<= 1) m = fmaxf(m, __shfl_xor(m, off));
  float lsum = 0.f;
#pragma unroll
  for (int st = 0; st < 4; ++st) {
    float p = __expf(sc[st] - m);
    Ps[w][st * 64 + ln] = p;
    lsum += p;
  }
#pragma unroll
  for (int off = 1; off < 64; off <<= 1) lsum += __shfl_xor(lsum, off);
  if (ln == 0) {
    int prow = bh * UU + rg * 8 + w;
    pm[prow * 8 + ch] = m;
    pl[prow * 8 + ch] = lsum;
  }
  __syncthreads();

  // ---- PV: wave = (rowgroup rw of 4 rows) x (col quarter cq) ----
  int rw = w >> 2, cq = w & 3;
  int cg = ln >> 4, d4 = ln & 15;
  float4 o0 = {0,0,0,0}, o1 = {0,0,0,0}, o2 = {0,0,0,0}, o3 = {0,0,0,0};
  int vb = (((b << 11) + l0 + cq * 64) << 7) + (h << 4);
  const float4* V4 = (const float4*)V;
#pragma unroll
  for (int i = 0; i < 16; ++i) {
    int c = i * 4 + cg;
    float4 v4 = V4[vb + c * 128 + d4];
    float p0 = Ps[rw * 4 + 0][cq * 64 + c];
    float p1 = Ps[rw * 4 + 1][cq * 64 + c];
    float p2 = Ps[rw * 4 + 2][cq * 64 + c];
    float p3 = Ps[rw * 4 + 3][cq * 64 + c];
    o0.x += p0 * v4.x; o0.y += p0 * v4.y; o0.z += p0 * v4.z; o0.w += p0 * v4.w;
    o1.x += p1 * v4.x; o1.y += p1 * v4.y; o1.z += p1 * v4.z; o1.w += p1 * v4.w;
    o2.x += p2 * v4.x; o2.y += p2 * v4.y; o2.z += p2 * v4.z; o2.w += p2 * v4.w;
    o3.x += p3 * v4.x; o3.y += p3 * v4.y; o3.z += p3 * v4.z; o3.w += p3 * v4.w;
  }
#pragma unroll
  for (int off = 16; off <= 32; off <<= 1) {
    o0.x += __shfl_xor(o0.x, off); o0.y += __shfl_xor(o0.y, off);
    o0.z += __shfl_xor(o0.z, off); o0.w += __shfl_xor(o0.w, off);
    o1.x += __shfl_xor(o1.x, off); o1.y += __shfl_xor(o1.y, off);
    o1.z += __shfl_xor(o1.z, off); o1.w += __shfl_xor(o1.w, off);
    o2.x += __shfl_xor(o2.x, off); o2.y += __shfl_xor(o2.y, off);
    o2.z += __shfl_xor(o2.z, off); o2.w += __shfl_xor(o2.w, off);
    o3.x += __shfl_xor(o3.x, off); o3.y += __shfl_xor(o3.y, off);
    o3.z += __shfl_xor(o3.z, off); o3.w += __shfl_xor(o3.w, off);
  }
  if (cg == 0) {
    Os4[cq][rw][0][d4] = o0;
    Os4[cq][rw][1][d4] = o1;
    Os4[cq][rw][2][d4] = o2;
    Os4[cq][rw][3][d4] = o3;
  }
  __syncthreads();

  if (t < 128) {
    int r = t >> 4, dd = t & 15;
    float4 a = Os4[0][r >> 2][r & 3][dd];
    float4 bq = Os4[1][r >> 2][r & 3][dd];
    float4 cc = Os4[2][r >> 2][r & 3][dd];
    float4 dq = Os4[3][r >> 2][r & 3][dd];
    float4 s;
    s.x = a.x + bq.x + cc.x + dq.x;
    s.y = a.y + bq.y + cc.y + dq.y;
    s.z = a.z + bq.z + cc.z + dq.z;
    s.w = a.w + bq.w + cc.w + dq.w;
    int prow = bh * UU + rg * 8 + r;
    pO4[(prow * 8 + ch) * 16 + dd] = s;
  }
}

// ---------------- Kernel 6: merge chunk partials ----------------
__global__ __launch_bounds__(256) void k_comb(
    const float* __restrict__ pm, const float* __restrict__ pl,
    const float* __restrict__ pO, const int* __restrict__ Mtop,
    float* __restrict__ out)
{
  int row = blockIdx.x * 4 + (threadIdx.x >> 6);  // 0..1279
  int ln = threadIdx.x & 63;
  int bh = row / UU, r40 = row % UU;
  float mm[8];
#pragma unroll
  for (int c = 0; c < 8; ++c) mm[c] = pm[row * 8 + c];
  float ms = mm[0];
#pragma unroll
  for (int c = 1; c < 8; ++c) ms = fmaxf(ms, mm[c]);
  float wsum = 0.f, o = 0.f;
#pragma unroll
  for (int c = 0; c < 8; ++c) {
    float wc = __expf(mm[c] - ms);
    wsum += wc * pl[row * 8 + c];
    o += wc * pO[(row * 8 + c) * 64 + ln];
  }
  int gq = Mtop[bh * UU + r40];
  out[((bh * LL + gq) << 6) + ln] = o / wsum;
}

extern "C" void kernel_launch(void* const* d_in, const int* in_sizes, int n_in,
                              void* d_out, int out_size, void* d_ws, size_t ws_size,
                              hipStream_t stream)
{
  (void)in_sizes; (void)n_in; (void)out_size; (void)ws_size;
  const float* Q = (const float*)d_in[0];
  const float* K = (const float*)d_in[1];
  const float* V = (const float*)d_in[2];
  const int* idxs = (const int*)d_in[3];
  float* out = (float*)d_out;

  float* wsf = (float*)d_ws;
  float* M     = wsf;                   // 65536
  float* part  = wsf + 65536;           // 16384
  int*   Mtop  = (int*)(wsf + 83968);   // 1280
  float* pm    = wsf + 85248;           // 10240
  float* pl    = wsf + 95488;           // 10240
  float* pO    = wsf + 105728;          // 655360

  k_m    <<<8192, 512, 0, stream>>>(Q, K, idxs, M);
  k_topk <<<32,   256, 0, stream>>>(M, Mtop);
  k_vpart<<<256,  256, 0, stream>>>(V, part);
  k_fill <<<4096, 256, 0, stream>>>((const float4*)part, (float4*)out);
  k_attn2<<<1280, 512, 0, stream>>>(Q, K, V, Mtop, pm, pl, (float4*)pO);
  k_comb <<<320,  256, 0, stream>>>(pm, pl, pO, Mtop, out);
}

// Round 4
// 207.965 us; speedup vs baseline: 1.2527x; 1.0371x over previous
//
#include <hip/hip_runtime.h>
#include <math.h>

#define LL 2048
#define HH 8
#define DD 64
#define SK 40
#define UU 40
#define SCALE 0.125f

// layouts: Q/K/V [b][l][h][d]; out [b][h][l][d]
// ws: M 65536 | part 16384 | (unused 2048) | Mtop 1280i | pm 10240 | pl 10240 | pO 655360

// ---------------- Kernel 1: sampled scores -> M ----------------
// XCD-pinned: xcd = bx&7 owns b = xcd>>1 (per-XCD gather working set = K[b] = 4MB = L2).
// One wave = one (b,l) row, ALL 8 heads: lane = h*8 + dg (dg = 8 consecutive d).
// One sample's K line (2KB contiguous) = exactly 2 coalesced float4 wave-loads.
// Samples batched x8 in explicit register arrays for deep MLP.
__global__ __launch_bounds__(512, 4) void k_m(
    const float* __restrict__ Q, const float* __restrict__ K,
    const int* __restrict__ idxs, float* __restrict__ Mout)
{
  __shared__ int sidx[8 * SK];
  int bx = blockIdx.x;
  int xcd = bx & 7, slot = bx >> 3;        // 1024 blocks -> slot 0..127
  int b = xcd >> 1;
  int l0 = ((xcd & 1) << 10) | (slot << 3);
  int t = threadIdx.x;
  int w = t >> 6, lane = t & 63;
  int l = l0 + w;
  int h = lane >> 3, dg = lane & 7;

  if (t < 8 * SK) sidx[t] = idxs[l0 * SK + t];

  const float4* Q4 = (const float4*)Q;
  int qoff = (((b << 11) + l) << 7) + (h << 4) + (dg << 1);
  float4 q0 = Q4[qoff], q1 = Q4[qoff + 1];

  const float4* K4 = (const float4*)K;
  int kbb = b << 18;                        // b * 2048 rows * 128 f4
  int klo = (h << 4) + (dg << 1);

  __syncthreads();

  float mx = -INFINITY, sum = 0.f;
#pragma unroll
  for (int s0 = 0; s0 < SK; s0 += 8) {
    float4 ka[8], kc[8];
#pragma unroll
    for (int j = 0; j < 8; ++j) {
      int idx = sidx[w * SK + s0 + j];
      int off = kbb + (idx << 7) + klo;
      ka[j] = K4[off];
      kc[j] = K4[off + 1];
    }
#pragma unroll
    for (int j = 0; j < 8; ++j) {
      float p = q0.x * ka[j].x + q0.y * ka[j].y + q0.z * ka[j].z + q0.w * ka[j].w
              + q1.x * kc[j].x + q1.y * kc[j].y + q1.z * kc[j].z + q1.w * kc[j].w;
      p += __shfl_xor(p, 1);
      p += __shfl_xor(p, 2);
      p += __shfl_xor(p, 4);
      mx = fmaxf(mx, p);
      sum += p;
    }
  }
  if (dg == 0) Mout[((b * HH + h) << 11) + l] = mx - sum * (1.0f / (float)LL);
}

// ---------------- Kernel 2: top-40 per (b,h), 4 waves ----------------
__global__ __launch_bounds__(256) void k_topk(
    const float* __restrict__ Mv, int* __restrict__ Mtop)
{
  __shared__ float sv[LL];
  __shared__ float wm[4];
  __shared__ int wi[4];
  int bh = blockIdx.x;
  int t = threadIdx.x, w = t >> 6, ln = t & 63;
  for (int i = t; i < LL; i += 256) sv[i] = Mv[bh * LL + i];
  __syncthreads();
  for (int r = 0; r < UU; ++r) {
    float bv = -INFINITY; int bi = 0;
#pragma unroll
    for (int j = 0; j < 8; ++j) {
      int i = t + (j << 8);
      float v = sv[i];
      if (v > bv) { bv = v; bi = i; }
    }
#pragma unroll
    for (int off = 1; off < 64; off <<= 1) {
      float ov = __shfl_xor(bv, off);
      int oi = __shfl_xor(bi, off);
      if (ov > bv || (ov == bv && oi < bi)) { bv = ov; bi = oi; }
    }
    if (ln == 0) { wm[w] = bv; wi[w] = bi; }
    __syncthreads();
    if (t == 0) {
      float Bv = wm[0]; int Bi = wi[0];
#pragma unroll
      for (int k = 1; k < 4; ++k)
        if (wm[k] > Bv || (wm[k] == Bv && wi[k] < Bi)) { Bv = wm[k]; Bi = wi[k]; }
      Mtop[bh * UU + r] = Bi;
      sv[Bi] = -INFINITY;
    }
    __syncthreads();
  }
}

// ---------------- Kernel 3: partial V sums ----------------
__global__ __launch_bounds__(256) void k_vpart(
    const float* __restrict__ V, float* __restrict__ part)
{
  int blk = blockIdx.x;
  int bh = blk >> 3, c = blk & 7;
  int b = bh >> 3, h = bh & 7;
  int t = threadIdx.x, d = t & 63, w = t >> 6;
  int l0 = (c << 8) + (w << 6);
  int base = (b << 20) + (l0 << 9) + (h << 6) + d;
  float a0 = 0, a1 = 0, a2 = 0, a3 = 0;
  for (int j = 0; j < 64; j += 4) {
    a0 += V[base + ((j + 0) << 9)];
    a1 += V[base + ((j + 1) << 9)];
    a2 += V[base + ((j + 2) << 9)];
    a3 += V[base + ((j + 3) << 9)];
  }
  __shared__ float sm[4][64];
  sm[w][d] = a0 + a1 + a2 + a3;
  __syncthreads();
  if (t < 64) part[(blk << 6) + t] = sm[0][t] + sm[1][t] + sm[2][t] + sm[3][t];
}

// ---------------- Kernel 4: Vmean (fused) + broadcast fill ----------------
__global__ __launch_bounds__(256) void k_fill(
    const float4* __restrict__ part4, float4* __restrict__ out4)
{
  int i = blockIdx.x * 256 + threadIdx.x;
  int bh = i >> 15;
  __shared__ float4 vm[16];
  if (threadIdx.x < 16) {
    int d4 = threadIdx.x;
    float4 s = {0, 0, 0, 0};
#pragma unroll
    for (int c = 0; c < 8; ++c) {
      float4 p = part4[((bh << 3) + c) * 16 + d4];
      s.x += p.x; s.y += p.y; s.z += p.z; s.w += p.w;
    }
    const float inv = 1.0f / (float)LL;
    s.x *= inv; s.y *= inv; s.z *= inv; s.w *= inv;
    vm[d4] = s;
  }
  __syncthreads();
  out4[i] = vm[i & 15];
}

// ---------------- Kernel 5: split-K attention partials ----------------
// XCD-pinned: ch = bx&7; per-XCD working set = 32bh * 128KB = 4MB = L2.
__global__ __launch_bounds__(512) void k_attn2(
    const float* __restrict__ Q, const float* __restrict__ K,
    const float* __restrict__ V, const int* __restrict__ Mtop,
    float* __restrict__ pm, float* __restrict__ pl, float4* __restrict__ pO4)
{
  __shared__ float4 Ks4[1024];        // swizzled: [col*16 + (d4^(col&7))]
  __shared__ float Ps[8][256];
  __shared__ float4 Os4[4][2][4][16]; // [cq][rw][r][d4]
  __shared__ int gqi[8];

  int bx = blockIdx.x;
  int ch = bx & 7;
  int slot = bx >> 3;                 // 0..159
  int bh = slot / 5, rg = slot % 5;
  int b = bh >> 3, h = bh & 7;
  int t = threadIdx.x;
  int w = t >> 6, ln = t & 63;
  int l0 = ch << 8;

  if (t < 8) gqi[t] = Mtop[bh * UU + rg * 8 + t];
  __syncthreads();

  float4 qv[16];
  {
    const float4* qrow = (const float4*)Q + (((b << 11) + gqi[w]) << 7) + (h << 4);
#pragma unroll
    for (int i = 0; i < 16; ++i) qv[i] = qrow[i];
  }

  const float4* K4 = (const float4*)K;
  int kbase = (((b << 11) + l0) << 7) + (h << 4);
  int col0 = t >> 4, d40 = t & 15;
  int sw0 = col0 * 16 + (d40 ^ (col0 & 7));
  float4 g0 = K4[kbase + col0 * 128 + d40];
  float4 g1 = K4[kbase + (col0 + 32) * 128 + d40];

  float sc[4];
#pragma unroll
  for (int st = 0; st < 4; ++st) {
    __syncthreads();
    Ks4[sw0] = g0;
    Ks4[sw0 + 512] = g1;
    float4 n0, n1;
    if (st < 3) {
      int lr = (st + 1) * 64;
      n0 = K4[kbase + (lr + col0) * 128 + d40];
      n1 = K4[kbase + (lr + col0 + 32) * 128 + d40];
    }
    __syncthreads();
    float s = 0.f;
#pragma unroll
    for (int d4 = 0; d4 < 16; ++d4) {
      float4 kv = Ks4[ln * 16 + (d4 ^ (ln & 7))];
      s += qv[d4].x * kv.x + qv[d4].y * kv.y + qv[d4].z * kv.z + qv[d4].w * kv.w;
    }
    sc[st] = s * SCALE;
    g0 = n0; g1 = n1;
  }

  float m = fmaxf(fmaxf(sc[0], sc[1]), fmaxf(sc[2], sc[3]));
#pragma unroll
  for (int off = 1; off < 64; off <<= 1) m = fmaxf(m, __shfl_xor(m, off));
  float lsum = 0.f;
#pragma unroll
  for (int st = 0; st < 4; ++st) {
    float p = __expf(sc[st] - m);
    Ps[w][st * 64 + ln] = p;
    lsum += p;
  }
#pragma unroll
  for (int off = 1; off < 64; off <<= 1) lsum += __shfl_xor(lsum, off);
  if (ln == 0) {
    int prow = bh * UU + rg * 8 + w;
    pm[prow * 8 + ch] = m;
    pl[prow * 8 + ch] = lsum;
  }
  __syncthreads();

  int rw = w >> 2, cq = w & 3;
  int cg = ln >> 4, d4 = ln & 15;
  float4 o0 = {0,0,0,0}, o1 = {0,0,0,0}, o2 = {0,0,0,0}, o3 = {0,0,0,0};
  int vb = (((b << 11) + l0 + cq * 64) << 7) + (h << 4);
  const float4* V4 = (const float4*)V;
#pragma unroll
  for (int i = 0; i < 16; ++i) {
    int c = i * 4 + cg;
    float4 v4 = V4[vb + c * 128 + d4];
    float p0 = Ps[rw * 4 + 0][cq * 64 + c];
    float p1 = Ps[rw * 4 + 1][cq * 64 + c];
    float p2 = Ps[rw * 4 + 2][cq * 64 + c];
    float p3 = Ps[rw * 4 + 3][cq * 64 + c];
    o0.x += p0 * v4.x; o0.y += p0 * v4.y; o0.z += p0 * v4.z; o0.w += p0 * v4.w;
    o1.x += p1 * v4.x; o1.y += p1 * v4.y; o1.z += p1 * v4.z; o1.w += p1 * v4.w;
    o2.x += p2 * v4.x; o2.y += p2 * v4.y; o2.z += p2 * v4.z; o2.w += p2 * v4.w;
    o3.x += p3 * v4.x; o3.y += p3 * v4.y; o3.z += p3 * v4.z; o3.w += p3 * v4.w;
  }
#pragma unroll
  for (int off = 16; off <= 32; off <<= 1) {
    o0.x += __shfl_xor(o0.x, off); o0.y += __shfl_xor(o0.y, off);
    o0.z += __shfl_xor(o0.z, off); o0.w += __shfl_xor(o0.w, off);
    o1.x += __shfl_xor(o1.x, off); o1.y += __shfl_xor(o1.y, off);
    o1.z += __shfl_xor(o1.z, off); o1.w += __shfl_xor(o1.w, off);
    o2.x += __shfl_xor(o2.x, off); o2.y += __shfl_xor(o2.y, off);
    o2.z += __shfl_xor(o2.z, off); o2.w += __shfl_xor(o2.w, off);
    o3.x += __shfl_xor(o3.x, off); o3.y += __shfl_xor(o3.y, off);
    o3.z += __shfl_xor(o3.z, off); o3.w += __shfl_xor(o3.w, off);
  }
  if (cg == 0) {
    Os4[cq][rw][0][d4] = o0;
    Os4[cq][rw][1][d4] = o1;
    Os4[cq][rw][2][d4] = o2;
    Os4[cq][rw][3][d4] = o3;
  }
  __syncthreads();

  if (t < 128) {
    int r = t >> 4, dd = t & 15;
    float4 a = Os4[0][r >> 2][r & 3][dd];
    float4 bq = Os4[1][r >> 2][r & 3][dd];
    float4 cc = Os4[2][r >> 2][r & 3][dd];
    float4 dq = Os4[3][r >> 2][r & 3][dd];
    float4 s;
    s.x = a.x + bq.x + cc.x + dq.x;
    s.y = a.y + bq.y + cc.y + dq.y;
    s.z = a.z + bq.z + cc.z + dq.z;
    s.w = a.w + bq.w + cc.w + dq.w;
    int prow = bh * UU + rg * 8 + r;
    pO4[(prow * 8 + ch) * 16 + dd] = s;
  }
}

// ---------------- Kernel 6: merge chunk partials ----------------
__global__ __launch_bounds__(256) void k_comb(
    const float* __restrict__ pm, const float* __restrict__ pl,
    const float* __restrict__ pO, const int* __restrict__ Mtop,
    float* __restrict__ out)
{
  int row = blockIdx.x * 4 + (threadIdx.x >> 6);  // 0..1279
  int ln = threadIdx.x & 63;
  int bh = row / UU, r40 = row % UU;
  float mm[8];
#pragma unroll
  for (int c = 0; c < 8; ++c) mm[c] = pm[row * 8 + c];
  float ms = mm[0];
#pragma unroll
  for (int c = 1; c < 8; ++c) ms = fmaxf(ms, mm[c]);
  float wsum = 0.f, o = 0.f;
#pragma unroll
  for (int c = 0; c < 8; ++c) {
    float wc = __expf(mm[c] - ms);
    wsum += wc * pl[row * 8 + c];
    o += wc * pO[(row * 8 + c) * 64 + ln];
  }
  int gq = Mtop[bh * UU + r40];
  out[((bh * LL + gq) << 6) + ln] = o / wsum;
}

extern "C" void kernel_launch(void* const* d_in, const int* in_sizes, int n_in,
                              void* d_out, int out_size, void* d_ws, size_t ws_size,
                              hipStream_t stream)
{
  (void)in_sizes; (void)n_in; (void)out_size; (void)ws_size;
  const float* Q = (const float*)d_in[0];
  const float* K = (const float*)d_in[1];
  const float* V = (const float*)d_in[2];
  const int* idxs = (const int*)d_in[3];
  float* out = (float*)d_out;

  float* wsf = (float*)d_ws;
  float* M     = wsf;                   // 65536
  float* part  = wsf + 65536;           // 16384
  int*   Mtop  = (int*)(wsf + 83968);   // 1280
  float* pm    = wsf + 85248;           // 10240
  float* pl    = wsf + 95488;           // 10240
  float* pO    = wsf + 105728;          // 655360

  k_m    <<<1024, 512, 0, stream>>>(Q, K, idxs, M);
  k_topk <<<32,   256, 0, stream>>>(M, Mtop);
  k_vpart<<<256,  256, 0, stream>>>(V, part);
  k_fill <<<4096, 256, 0, stream>>>((const float4*)part, (float4*)out);
  k_attn2<<<1280, 512, 0, stream>>>(Q, K, V, Mtop, pm, pl, (float4*)pO);
  k_comb <<<320,  256, 0, stream>>>(pm, pl, pO, Mtop, out);
}

// Round 5
// 202.727 us; speedup vs baseline: 1.2850x; 1.0258x over previous
//
#include <hip/hip_runtime.h>
#include <math.h>

#define LL 2048
#define HH 8
#define DD 64
#define SK 40
#define UU 40
#define SCALE 0.125f

__device__ __forceinline__ float dot4(float4 a, float4 b) {
  return a.x * b.x + a.y * b.y + a.z * b.z + a.w * b.w;
}

// layouts: Q/K/V [b][l][h][d]; out [b][h][l][d]
// ws: M 65536 | part 16384 | (unused) | Mtop 1280i | pm 10240 | pl 10240 | pO 655360

// ================ Kernel A: sampled scores -> M  (+ fused V partial sums) ================
// k_m role (bx < 2048): XCD-pinned xcd=bx&7, b=xcd>>1 (per-XCD gather set = K[b] = 4MB = L2).
// Block = 4 l-rows x 2 sample-halves (8 waves). Lane = sp*32 + h*4 + dg:
// 16 dims/lane via interleaved f4 slots {dg, dg+4, dg+8, dg+12} -> 2 dependent shuffles per
// sample PAIR; per-instruction coalescing stays 2 requests/cacheline.
__global__ __launch_bounds__(512, 4) void k_A(
    const float* __restrict__ Q, const float* __restrict__ K,
    const float* __restrict__ V, const int* __restrict__ idxs,
    float* __restrict__ Mout, float* __restrict__ part)
{
  int bx = blockIdx.x;
  int t = threadIdx.x;

  if (bx < 2048) {
    // ---------------- k_m ----------------
    __shared__ int sidx[4 * SK];
    __shared__ float wred[2][4][2][8];   // [mx|sum][lpos][half][h]

    int xcd = bx & 7, slot = bx >> 3;    // slot 0..255
    int b = xcd >> 1;
    int l0 = ((xcd & 1) << 10) | (slot << 2);
    int w = t >> 6, lane = t & 63;
    int lpos = w >> 1, half = w & 1;
    int l = l0 + lpos;
    int h = (lane >> 2) & 7, dg = lane & 3, sp = lane >> 5;

    if (t < 4 * SK) sidx[t] = idxs[l0 * SK + t];

    const float4* Q4 = (const float4*)Q;
    int qb = (((b << 11) + l) << 7) + (h << 4) + dg;
    float4 q0 = Q4[qb], q1 = Q4[qb + 4], q2 = Q4[qb + 8], q3 = Q4[qb + 12];

    const float4* K4 = (const float4*)K;
    int kbb = (b << 18) + (h << 4) + dg;

    __syncthreads();

    const int* hidx = &sidx[lpos * SK + half * 20];
    float mx = -INFINITY, sum = 0.f;
#pragma unroll
    for (int pp = 0; pp < 10; pp += 2) {
      int i0 = hidx[pp * 2 + sp];
      int i1 = hidx[pp * 2 + 2 + sp];
      int o0 = kbb + (i0 << 7);
      int o1 = kbb + (i1 << 7);
      float4 a0 = K4[o0], a1 = K4[o0 + 4], a2 = K4[o0 + 8], a3 = K4[o0 + 12];
      float4 c0 = K4[o1], c1 = K4[o1 + 4], c2 = K4[o1 + 8], c3 = K4[o1 + 12];
      float p = dot4(q0, a0) + dot4(q1, a1) + dot4(q2, a2) + dot4(q3, a3);
      float r = dot4(q0, c0) + dot4(q1, c1) + dot4(q2, c2) + dot4(q3, c3);
      p += __shfl_xor(p, 1); p += __shfl_xor(p, 2);
      r += __shfl_xor(r, 1); r += __shfl_xor(r, 2);
      mx = fmaxf(mx, fmaxf(p, r));
      sum += p + r;
    }
    mx = fmaxf(mx, __shfl_xor(mx, 32));
    sum += __shfl_xor(sum, 32);
    if ((lane & 35) == 0) {              // sp==0 && dg==0
      wred[0][lpos][half][h] = mx;
      wred[1][lpos][half][h] = sum;
    }
    __syncthreads();
    if (t < 32) {
      int lp = t >> 3, hh = t & 7;
      float M0 = fmaxf(wred[0][lp][0][hh], wred[0][lp][1][hh]);
      float S0 = wred[1][lp][0][hh] + wred[1][lp][1][hh];
      Mout[((b * HH + hh) << 11) + (l0 + lp)] = M0 - S0 * (1.0f / (float)LL);
    }
  } else {
    // ---------------- vpart (512-thread): blk = (bh<<3)+chunk ----------------
    __shared__ float sm[8][64];
    int blk = bx - 2048;                 // 0..255
    int bh = blk >> 3, c = blk & 7;
    int b = bh >> 3, h = bh & 7;
    int w = t >> 6, d = t & 63;
    int l0 = (c << 8) + (w << 5);
    int base = (b << 20) + (l0 << 9) + (h << 6) + d;
    float a0 = 0, a1 = 0, a2 = 0, a3 = 0;
#pragma unroll
    for (int j = 0; j < 32; j += 4) {
      a0 += V[base + ((j + 0) << 9)];
      a1 += V[base + ((j + 1) << 9)];
      a2 += V[base + ((j + 2) << 9)];
      a3 += V[base + ((j + 3) << 9)];
    }
    sm[w][d] = a0 + a1 + a2 + a3;
    __syncthreads();
    if (t < 64) {
      float s = 0;
#pragma unroll
      for (int i = 0; i < 8; ++i) s += sm[i][t];
      part[(blk << 6) + t] = s;
    }
  }
}

// ================ Kernel B: top-40 per (b,h)  (+ fused Vmean broadcast fill) ================
__global__ __launch_bounds__(256) void k_B(
    const float* __restrict__ Mv, int* __restrict__ Mtop,
    const float4* __restrict__ part4, float4* __restrict__ out4)
{
  int bx = blockIdx.x;
  int t = threadIdx.x;

  if (bx < 32) {
    // ---------------- topk ----------------
    __shared__ float sv[LL];
    __shared__ float wm[4];
    __shared__ int wi[4];
    int bh = bx;
    int w = t >> 6, ln = t & 63;
    for (int i = t; i < LL; i += 256) sv[i] = Mv[bh * LL + i];
    __syncthreads();
    for (int r = 0; r < UU; ++r) {
      float bv = -INFINITY; int bi = 0;
#pragma unroll
      for (int j = 0; j < 8; ++j) {
        int i = t + (j << 8);
        float v = sv[i];
        if (v > bv) { bv = v; bi = i; }
      }
#pragma unroll
      for (int off = 1; off < 64; off <<= 1) {
        float ov = __shfl_xor(bv, off);
        int oi = __shfl_xor(bi, off);
        if (ov > bv || (ov == bv && oi < bi)) { bv = ov; bi = oi; }
      }
      if (ln == 0) { wm[w] = bv; wi[w] = bi; }
      __syncthreads();
      if (t == 0) {
        float Bv = wm[0]; int Bi = wi[0];
#pragma unroll
        for (int k = 1; k < 4; ++k)
          if (wm[k] > Bv || (wm[k] == Bv && wi[k] < Bi)) { Bv = wm[k]; Bi = wi[k]; }
        Mtop[bh * UU + r] = Bi;
        sv[Bi] = -INFINITY;
      }
      __syncthreads();
    }
  } else {
    // ---------------- Vmean + fill ----------------
    __shared__ float4 vm[16];
    int i = (bx - 32) * 256 + t;         // float4 index, 0..1048575
    int bh = i >> 15;
    if (t < 16) {
      int d4 = t;
      float4 s = {0, 0, 0, 0};
#pragma unroll
      for (int c = 0; c < 8; ++c) {
        float4 p = part4[((bh << 3) + c) * 16 + d4];
        s.x += p.x; s.y += p.y; s.z += p.z; s.w += p.w;
      }
      const float inv = 1.0f / (float)LL;
      s.x *= inv; s.y *= inv; s.z *= inv; s.w *= inv;
      vm[d4] = s;
    }
    __syncthreads();
    out4[i] = vm[i & 15];
  }
}

// ================ Kernel C: split-K attention partials ================
// XCD-pinned: ch = bx&7; per-XCD working set = 32bh * 128KB = 4MB = L2.
__global__ __launch_bounds__(512) void k_attn2(
    const float* __restrict__ Q, const float* __restrict__ K,
    const float* __restrict__ V, const int* __restrict__ Mtop,
    float* __restrict__ pm, float* __restrict__ pl, float4* __restrict__ pO4)
{
  __shared__ float4 Ks4[1024];        // swizzled: [col*16 + (d4^(col&7))]
  __shared__ float Ps[8][256];
  __shared__ float4 Os4[4][2][4][16]; // [cq][rw][r][d4]
  __shared__ int gqi[8];

  int bx = blockIdx.x;
  int ch = bx & 7;
  int slot = bx >> 3;                 // 0..159
  int bh = slot / 5, rg = slot % 5;
  int b = bh >> 3, h = bh & 7;
  int t = threadIdx.x;
  int w = t >> 6, ln = t & 63;
  int l0 = ch << 8;

  if (t < 8) gqi[t] = Mtop[bh * UU + rg * 8 + t];
  __syncthreads();

  float4 qv[16];
  {
    const float4* qrow = (const float4*)Q + (((b << 11) + gqi[w]) << 7) + (h << 4);
#pragma unroll
    for (int i = 0; i < 16; ++i) qv[i] = qrow[i];
  }

  const float4* K4 = (const float4*)K;
  int kbase = (((b << 11) + l0) << 7) + (h << 4);
  int col0 = t >> 4, d40 = t & 15;
  int sw0 = col0 * 16 + (d40 ^ (col0 & 7));
  float4 g0 = K4[kbase + col0 * 128 + d40];
  float4 g1 = K4[kbase + (col0 + 32) * 128 + d40];

  float sc[4];
#pragma unroll
  for (int st = 0; st < 4; ++st) {
    __syncthreads();
    Ks4[sw0] = g0;
    Ks4[sw0 + 512] = g1;
    float4 n0, n1;
    if (st < 3) {
      int lr = (st + 1) * 64;
      n0 = K4[kbase + (lr + col0) * 128 + d40];
      n1 = K4[kbase + (lr + col0 + 32) * 128 + d40];
    }
    __syncthreads();
    float s = 0.f;
#pragma unroll
    for (int d4 = 0; d4 < 16; ++d4) {
      float4 kv = Ks4[ln * 16 + (d4 ^ (ln & 7))];
      s += qv[d4].x * kv.x + qv[d4].y * kv.y + qv[d4].z * kv.z + qv[d4].w * kv.w;
    }
    sc[st] = s * SCALE;
    g0 = n0; g1 = n1;
  }

  float m = fmaxf(fmaxf(sc[0], sc[1]), fmaxf(sc[2], sc[3]));
#pragma unroll
  for (int off = 1; off < 64; off <<= 1) m = fmaxf(m, __shfl_xor(m, off));
  float lsum = 0.f;
#pragma unroll
  for (int st = 0; st < 4; ++st) {
    float p = __expf(sc[st] - m);
    Ps[w][st * 64 + ln] = p;
    lsum += p;
  }
#pragma unroll
  for (int off = 1; off < 64; off <<= 1) lsum += __shfl_xor(lsum, off);
  if (ln == 0) {
    int prow = bh * UU + rg * 8 + w;
    pm[prow * 8 + ch] = m;
    pl[prow * 8 + ch] = lsum;
  }
  __syncthreads();

  int rw = w >> 2, cq = w & 3;
  int cg = ln >> 4, d4 = ln & 15;
  float4 o0 = {0,0,0,0}, o1 = {0,0,0,0}, o2 = {0,0,0,0}, o3 = {0,0,0,0};
  int vb = (((b << 11) + l0 + cq * 64) << 7) + (h << 4);
  const float4* V4 = (const float4*)V;
#pragma unroll
  for (int i = 0; i < 16; ++i) {
    int c = i * 4 + cg;
    float4 v4 = V4[vb + c * 128 + d4];
    float p0 = Ps[rw * 4 + 0][cq * 64 + c];
    float p1 = Ps[rw * 4 + 1][cq * 64 + c];
    float p2 = Ps[rw * 4 + 2][cq * 64 + c];
    float p3 = Ps[rw * 4 + 3][cq * 64 + c];
    o0.x += p0 * v4.x; o0.y += p0 * v4.y; o0.z += p0 * v4.z; o0.w += p0 * v4.w;
    o1.x += p1 * v4.x; o1.y += p1 * v4.y; o1.z += p1 * v4.z; o1.w += p1 * v4.w;
    o2.x += p2 * v4.x; o2.y += p2 * v4.y; o2.z += p2 * v4.z; o2.w += p2 * v4.w;
    o3.x += p3 * v4.x; o3.y += p3 * v4.y; o3.z += p3 * v4.z; o3.w += p3 * v4.w;
  }
#pragma unroll
  for (int off = 16; off <= 32; off <<= 1) {
    o0.x += __shfl_xor(o0.x, off); o0.y += __shfl_xor(o0.y, off);
    o0.z += __shfl_xor(o0.z, off); o0.w += __shfl_xor(o0.w, off);
    o1.x += __shfl_xor(o1.x, off); o1.y += __shfl_xor(o1.y, off);
    o1.z += __shfl_xor(o1.z, off); o1.w += __shfl_xor(o1.w, off);
    o2.x += __shfl_xor(o2.x, off); o2.y += __shfl_xor(o2.y, off);
    o2.z += __shfl_xor(o2.z, off); o2.w += __shfl_xor(o2.w, off);
    o3.x += __shfl_xor(o3.x, off); o3.y += __shfl_xor(o3.y, off);
    o3.z += __shfl_xor(o3.z, off); o3.w += __shfl_xor(o3.w, off);
  }
  if (cg == 0) {
    Os4[cq][rw][0][d4] = o0;
    Os4[cq][rw][1][d4] = o1;
    Os4[cq][rw][2][d4] = o2;
    Os4[cq][rw][3][d4] = o3;
  }
  __syncthreads();

  if (t < 128) {
    int r = t >> 4, dd = t & 15;
    float4 a = Os4[0][r >> 2][r & 3][dd];
    float4 bq = Os4[1][r >> 2][r & 3][dd];
    float4 cc = Os4[2][r >> 2][r & 3][dd];
    float4 dq = Os4[3][r >> 2][r & 3][dd];
    float4 s;
    s.x = a.x + bq.x + cc.x + dq.x;
    s.y = a.y + bq.y + cc.y + dq.y;
    s.z = a.z + bq.z + cc.z + dq.z;
    s.w = a.w + bq.w + cc.w + dq.w;
    int prow = bh * UU + rg * 8 + r;
    pO4[(prow * 8 + ch) * 16 + dd] = s;
  }
}

// ================ Kernel D: merge chunk partials ================
__global__ __launch_bounds__(256) void k_comb(
    const float* __restrict__ pm, const float* __restrict__ pl,
    const float* __restrict__ pO, const int* __restrict__ Mtop,
    float* __restrict__ out)
{
  int row = blockIdx.x * 4 + (threadIdx.x >> 6);  // 0..1279
  int ln = threadIdx.x & 63;
  int bh = row / UU, r40 = row % UU;
  float mm[8];
#pragma unroll
  for (int c = 0; c < 8; ++c) mm[c] = pm[row * 8 + c];
  float ms = mm[0];
#pragma unroll
  for (int c = 1; c < 8; ++c) ms = fmaxf(ms, mm[c]);
  float wsum = 0.f, o = 0.f;
#pragma unroll
  for (int c = 0; c < 8; ++c) {
    float wc = __expf(mm[c] - ms);
    wsum += wc * pl[row * 8 + c];
    o += wc * pO[(row * 8 + c) * 64 + ln];
  }
  int gq = Mtop[bh * UU + r40];
  out[((bh * LL + gq) << 6) + ln] = o / wsum;
}

extern "C" void kernel_launch(void* const* d_in, const int* in_sizes, int n_in,
                              void* d_out, int out_size, void* d_ws, size_t ws_size,
                              hipStream_t stream)
{
  (void)in_sizes; (void)n_in; (void)out_size; (void)ws_size;
  const float* Q = (const float*)d_in[0];
  const float* K = (const float*)d_in[1];
  const float* V = (const float*)d_in[2];
  const int* idxs = (const int*)d_in[3];
  float* out = (float*)d_out;

  float* wsf = (float*)d_ws;
  float* M     = wsf;                   // 65536
  float* part  = wsf + 65536;           // 16384
  int*   Mtop  = (int*)(wsf + 83968);   // 1280
  float* pm    = wsf + 85248;           // 10240
  float* pl    = wsf + 95488;           // 10240
  float* pO    = wsf + 105728;          // 655360

  k_A    <<<2304, 512, 0, stream>>>(Q, K, V, idxs, M, part);
  k_B    <<<4128, 256, 0, stream>>>(M, Mtop, (const float4*)part, (float4*)out);
  k_attn2<<<1280, 512, 0, stream>>>(Q, K, V, Mtop, pm, pl, (float4*)pO);
  k_comb <<<320,  256, 0, stream>>>(pm, pl, pO, Mtop, out);
}